// Round 2
// baseline (392.173 us; speedup 1.0000x reference)
//
#include <hip/hip_runtime.h>
#include <hip/hip_cooperative_groups.h>
#include <math.h>

namespace cg = cooperative_groups;

// CapsuleLayer dynamic routing — round 9: single cooperative kernel.
// B=64, N=4096, I=8, C=32, D=16, 3 routing iterations.
//
// Round-8 post-mortem: all 6 dispatches fell below the 42µs harness fills;
// kernel-work roofline sum ~= 100us vs 209.6us measured -> ~100us is
// inter-dispatch overhead (6 serially dependent nodes + tiny reduce grids).
// Round 9: fuse the whole pipeline into ONE hipLaunchCooperativeKernel.
// 256 blocks x 512 thr = 1 block/CU (co-residency guaranteed; round-8 body
// was 64 VGPR / 35KB LDS). grid.sync() replaces kernel boundaries; Wh/x stay
// L2-hot across passes (per-XCD Wh slice = 4 MiB = L2 size). Inner loops,
// MFMA layout, epilogue swizzle, squash math copied verbatim from round 8.
//
// ws: Wh fp16 [n][cj][i] 32 MiB | partial u32(h2) [bid][bl][cjp] 8 MiB |
//     OcumG fp16 [b][cj] 64 KiB  (40.07 MiB total)

typedef __fp16 h2 __attribute__((ext_vector_type(2)));
typedef __fp16 half4 __attribute__((ext_vector_type(4)));
typedef float f32x16 __attribute__((ext_vector_type(16)));

union U2 { h2 h; unsigned u; };

__device__ __forceinline__ float fdot2(h2 a, h2 b, float c) {
    return __builtin_amdgcn_fdot2(a, b, c, false);
}
__device__ __forceinline__ h2 uash2(unsigned u) { U2 t; t.u = u; return t.h; }

// ---- epilogue: stage h2 partial tile in LDS (XOR-swizzled), copy out ------
__device__ __forceinline__ void epilogue_store(const f32x16& acc0, const f32x16& acc1,
                                               int w, int bl, int hi, int t, int bid,
                                               unsigned* sep,
                                               unsigned* __restrict__ partial) {
    #pragma unroll
    for (int mt = 0; mt < 2; ++mt) {
        #pragma unroll
        for (int q = 0; q < 8; ++q) {
            const float e0 = mt ? acc1[2 * q] : acc0[2 * q];
            const float e1 = mt ? acc1[2 * q + 1] : acc0[2 * q + 1];
            U2 u; u.h = __builtin_amdgcn_cvt_pkrtz(e0, e1);
            const int cjp = w * 32 + mt * 16 + 4 * (q >> 1) + (q & 1) + 2 * hi;
            sep[bl * 256 + (cjp ^ bl)] = u.u;   // swizzle: conflict-free banks
        }
    }
    __syncthreads();
    const unsigned gbase = (unsigned)bid * 8192;
    #pragma unroll
    for (int u2 = 0; u2 < 16; ++u2) {
        const int idx = t + u2 * 512;
        const int ubl = idx >> 8, ucjp = idx & 255;
        partial[gbase + idx] = sep[ubl * 256 + (ucjp ^ ubl)];
    }
}

// ---- reduce + squash + Ocum update (blocks 0..31 active) ------------------
__device__ __forceinline__ void reduce_squash_body(const unsigned* __restrict__ partial32,
                                                   ushort* __restrict__ OcumG,
                                                   float* __restrict__ out,
                                                   int passIdx, int tidg) {
    if (tidg >= 16384) return;
    const int b = tidg >> 8, cjp = tidg & 255;
    const int bt = b >> 5, bl = b & 31;
    const unsigned base = (unsigned)bt * 1048576u + (unsigned)bl * 256u + (unsigned)cjp;
    float sx = 0.f, sy = 0.f;
    #pragma unroll 8
    for (int nb = 0; nb < 128; ++nb) {
        U2 v; v.u = partial32[base + nb * 8192];
        sx += (float)v.h.x;
        sy += (float)v.h.y;
    }
    float s2 = sx * sx + sy * sy;                    // 16 j live in 8 lanes
    s2 += __shfl_xor(s2, 1, 64);
    s2 += __shfl_xor(s2, 2, 64);
    s2 += __shfl_xor(s2, 4, 64);
    float scale = (s2 / (1.f + s2)) / sqrtf(s2 + 1e-7f);
    float o0 = scale * sx, o1 = scale * sy;

    unsigned* ocp = reinterpret_cast<unsigned*>(OcumG) + b * 256 + cjp;
    float a0 = o0, a1 = o1;
    if (passIdx) {
        U2 old; old.u = *ocp;
        a0 += (float)old.h.x;
        a1 += (float)old.h.y;
    }
    U2 nw; nw.h = __builtin_amdgcn_cvt_pkrtz(a0, a1);
    *ocp = nw.u;

    if (passIdx == 2) {
        out[b * 512 + cjp * 2] = o0;
        out[b * 512 + cjp * 2 + 1] = o1;
    }
}

// ---- the whole routing pipeline in one launch -----------------------------

__global__ __launch_bounds__(512, 1) void caps_routing(
    const float* __restrict__ W,      // [C][N][D][I] f32
    const float* __restrict__ x,      // [B][N][I] f32
    ushort* __restrict__ Wh,          // [N][CJ][I] fp16
    ushort* __restrict__ OcumG,       // [B][CJ] fp16
    unsigned* __restrict__ partial,   // [bid][bl 32][cjp 256] u32(h2)
    float* __restrict__ out)
{
    cg::grid_group grid = cg::this_grid();

    const int bid = blockIdx.x;
    const int bt = bid >> 7, nblk = bid & 127;
    const int n0 = nblk * 32;
    const int t = threadIdx.x, l = t & 63, w = t >> 6;
    const int bl = l & 31, hi = l >> 5;
    const int b = bt * 32 + bl;
    const int tidg = bid * 512 + t;

    __shared__ __align__(16) float pd[2][32][12];  // [buf][b][wave] e-partials
    __shared__ unsigned sep[8192];                 // 32KB epilogue staging

    const int cj0 = w * 64 + bl, cj1 = cj0 + 32;
    const float* xb = x + (size_t)b * 32768 + (size_t)n0 * 8 + hi * 4;
    const float* wb0 = W + (size_t)(cj0 >> 4) * 524288 + (size_t)n0 * 128 + (cj0 & 15) * 8 + hi * 4;
    const float* wb1 = W + (size_t)(cj1 >> 4) * 524288 + (size_t)n0 * 128 + (cj1 & 15) * 8 + hi * 4;
    ushort* whp0 = Wh + ((size_t)n0 * 512 + cj0) * 8 + hi * 4;
    ushort* whp1 = Wh + ((size_t)n0 * 512 + cj1) * 8 + hi * 4;

    f32x16 zero = {};

    // ================= PASS 0: uniform coupling, W f32->fp16 convert ========
    {
        f32x16 acc0 = {}, acc1 = {};
        float4 wv0 = *reinterpret_cast<const float4*>(wb0);
        float4 wv1 = *reinterpret_cast<const float4*>(wb1);
        float4 xv  = *reinterpret_cast<const float4*>(xb);
        #pragma unroll 1
        for (int s = 0; s < 32; ++s) {
            float4 wv0n, wv1n, xvn;
            if (s < 31) {
                wv0n = *reinterpret_cast<const float4*>(wb0 + (s + 1) * 128);
                wv1n = *reinterpret_cast<const float4*>(wb1 + (s + 1) * 128);
                xvn  = *reinterpret_cast<const float4*>(xb + (s + 1) * 8);
            }
            half4 a0, a1, bf;
            a0[0] = (__fp16)wv0.x; a0[1] = (__fp16)wv0.y; a0[2] = (__fp16)wv0.z; a0[3] = (__fp16)wv0.w;
            a1[0] = (__fp16)wv1.x; a1[1] = (__fp16)wv1.y; a1[2] = (__fp16)wv1.z; a1[3] = (__fp16)wv1.w;
            bf[0] = (__fp16)xv.x;  bf[1] = (__fp16)xv.y;  bf[2] = (__fp16)xv.z;  bf[3] = (__fp16)xv.w;
            if (bt == 0) {  // fold W conversion into pass 0
                *reinterpret_cast<half4*>(whp0 + (size_t)s * 4096) = a0;
                *reinterpret_cast<half4*>(whp1 + (size_t)s * 4096) = a1;
            }
            acc0 = __builtin_amdgcn_mfma_f32_32x32x8f16(a0, bf, acc0, 0, 0, 0);
            acc1 = __builtin_amdgcn_mfma_f32_32x32x8f16(a1, bf, acc1, 0, 0, 0);
            wv0 = wv0n; wv1 = wv1n; xv = xvn;
        }
        #pragma unroll
        for (int r = 0; r < 16; ++r) { acc0[r] *= 0.03125f; acc1[r] *= 0.03125f; }
        epilogue_store(acc0, acc1, w, bl, hi, t, bid, sep, partial);
    }
    grid.sync();
    reduce_squash_body(partial, OcumG, out, 0, tidg);
    grid.sync();

    // ================= PASS 1,2: softmax coupling ===========================
    #pragma unroll 1
    for (int pass = 1; pass < 3; ++pass) {
        h2 oc[2][8];
        {
            const unsigned* og = reinterpret_cast<const unsigned*>(OcumG);
            #pragma unroll
            for (int mt = 0; mt < 2; ++mt) {
                const int cA = 4 * w + 2 * mt;
                const unsigned idx = (unsigned)b * 256 + cA * 8 + hi * 2;
                oc[mt][0] = uash2(og[idx]);      oc[mt][1] = uash2(og[idx + 1]);
                oc[mt][2] = uash2(og[idx + 4]);  oc[mt][3] = uash2(og[idx + 5]);
                oc[mt][4] = uash2(og[idx + 8]);  oc[mt][5] = uash2(og[idx + 9]);
                oc[mt][6] = uash2(og[idx + 12]); oc[mt][7] = uash2(og[idx + 13]);
            }
        }
        f32x16 acc0 = {}, acc1 = {};
        half4 a0 = *reinterpret_cast<const half4*>(whp0);
        half4 a1 = *reinterpret_cast<const half4*>(whp1);
        float4 xv = *reinterpret_cast<const float4*>(xb);
        #pragma unroll 1
        for (int s = 0; s < 32; ++s) {
            half4 a0n, a1n; float4 xvn;
            if (s < 31) {
                a0n = *reinterpret_cast<const half4*>(whp0 + (size_t)(s + 1) * 4096);
                a1n = *reinterpret_cast<const half4*>(whp1 + (size_t)(s + 1) * 4096);
                xvn = *reinterpret_cast<const float4*>(xb + (s + 1) * 8);
            }
            half4 bf;
            bf[0] = (__fp16)xv.x; bf[1] = (__fp16)xv.y; bf[2] = (__fp16)xv.z; bf[3] = (__fp16)xv.w;
            f32x16 d0 = __builtin_amdgcn_mfma_f32_32x32x8f16(a0, bf, zero, 0, 0, 0);
            f32x16 d1 = __builtin_amdgcn_mfma_f32_32x32x8f16(a1, bf, zero, 0, 0, 0);
            h2 h0[8], h1[8];
            #pragma unroll
            for (int q = 0; q < 8; ++q) {
                h0[q] = __builtin_amdgcn_cvt_pkrtz(d0[2 * q], d0[2 * q + 1]);
                h1[q] = __builtin_amdgcn_cvt_pkrtz(d1[2 * q], d1[2 * q + 1]);
            }
            float pA0 = fdot2(h0[3], oc[0][3], fdot2(h0[2], oc[0][2], fdot2(h0[1], oc[0][1], fdot2(h0[0], oc[0][0], 0.f))));
            float pB0 = fdot2(h0[7], oc[0][7], fdot2(h0[6], oc[0][6], fdot2(h0[5], oc[0][5], fdot2(h0[4], oc[0][4], 0.f))));
            float pA1 = fdot2(h1[3], oc[1][3], fdot2(h1[2], oc[1][2], fdot2(h1[1], oc[1][1], fdot2(h1[0], oc[1][0], 0.f))));
            float pB1 = fdot2(h1[7], oc[1][7], fdot2(h1[6], oc[1][6], fdot2(h1[5], oc[1][5], fdot2(h1[4], oc[1][4], 0.f))));
            pA0 += __shfl_xor(pA0, 32, 64);
            pB0 += __shfl_xor(pB0, 32, 64);
            pA1 += __shfl_xor(pA1, 32, 64);
            pB1 += __shfl_xor(pB1, 32, 64);
            float eA0 = __expf(pA0), eB0 = __expf(pB0), eA1 = __expf(pA1), eB1 = __expf(pB1);
            const int buf = s & 1;
            if (l < 32) pd[buf][bl][w] = eA0 + eB0 + eA1 + eB1;  // 4-c partial
            __syncthreads();
            const float4 q0 = *reinterpret_cast<const float4*>(&pd[buf][bl][0]);
            const float4 q1 = *reinterpret_cast<const float4*>(&pd[buf][bl][4]);
            const float rd = __builtin_amdgcn_rcpf(q0.x + q0.y + q0.z + q0.w +
                                                   q1.x + q1.y + q1.z + q1.w);
            const float cA0 = eA0 * rd, cB0 = eB0 * rd, cA1 = eA1 * rd, cB1 = eB1 * rd;
            #pragma unroll
            for (int r = 0; r < 8; ++r)  { acc0[r] += d0[r] * cA0; acc1[r] += d1[r] * cA1; }
            #pragma unroll
            for (int r = 8; r < 16; ++r) { acc0[r] += d0[r] * cB0; acc1[r] += d1[r] * cB1; }
            a0 = a0n; a1 = a1n; xv = xvn;
        }
        epilogue_store(acc0, acc1, w, bl, hi, t, bid, sep, partial);
        grid.sync();
        reduce_squash_body(partial, OcumG, out, pass, tidg);
        if (pass < 2) grid.sync();
    }
}

// ---- host ------------------------------------------------------------------

extern "C" void kernel_launch(void* const* d_in, const int* in_sizes, int n_in,
                              void* d_out, int out_size, void* d_ws, size_t ws_size,
                              hipStream_t stream) {
    const float* x = (const float*)d_in[0];
    const float* W = (const float*)d_in[1];
    float* out = (float*)d_out;

    char* ws = (char*)d_ws;
    ushort* Wh = (ushort*)ws;                                        // 32 MiB
    unsigned* partialU = (unsigned*)(ws + (size_t)32 * 1024 * 1024); // 8 MiB
    ushort* OcumG = (ushort*)(ws + (size_t)40 * 1024 * 1024);        // 64 KiB

    void* args[] = {(void*)&W, (void*)&x, (void*)&Wh, (void*)&OcumG,
                    (void*)&partialU, (void*)&out};
    hipLaunchCooperativeKernel(reinterpret_cast<void*>(caps_routing),
                               dim3(256), dim3(512), args, 0, stream);
}

// Round 3
// 206.304 us; speedup vs baseline: 1.9009x; 1.9009x over previous
//
#include <hip/hip_runtime.h>
#include <math.h>

// CapsuleLayer dynamic routing — round 10: occupancy fix, multi-dispatch.
// B=64, N=4096, I=8, C=32, D=16, 3 routing iterations.
//
// Round-9 post-mortem: cooperative fusion REGRESSED (300us kernel): grid.sync
// on 8 non-coherent XCDs costs ~40us each, and Occupancy 23% (= 1 block/CU,
// 8 waves) meant every per-n softmax __syncthreads stalled the whole CU
// (VALUBusy 8%). Round 10: revert to the verified 6-dispatch round-8
// structure, and halve the n-tile (NPB 32->16, grid 256->512) so TWO blocks
// co-reside per CU (launch_bounds(512,4): VGPR cap 128, LDS 2x35.8KB ok).
// Barriers and memory latency in one block now overlap with the other block.
// Partial buffer grows to 16 MiB (ws 48.07 MiB) -- runtime ws_size check
// falls back to the exact round-8 NPB=32 config if workspace is short.
//
// ws (NPB=16): Wh fp16 [n][cj][i] 32 MiB | partial u32(h2) [bid][bl][cjp]
//              16 MiB | OcumG fp16 [b][cj] 64 KiB  (48.07 MiB total)

typedef __fp16 h2 __attribute__((ext_vector_type(2)));
typedef __fp16 half4 __attribute__((ext_vector_type(4)));
typedef float f32x16 __attribute__((ext_vector_type(16)));

union U2 { h2 h; unsigned u; };

__device__ __forceinline__ float fdot2(h2 a, h2 b, float c) {
    return __builtin_amdgcn_fdot2(a, b, c, false);
}
__device__ __forceinline__ h2 uash2(unsigned u) { U2 t; t.u = u; return t.h; }

template <int PASS0, int NPB>
__global__ __launch_bounds__(512, 4) void fused_pass(
    const float* __restrict__ W,      // [C][N][D][I] f32
    const float* __restrict__ x,      // [B][N][I] f32
    ushort* __restrict__ Wh,          // [N][CJ][I] fp16
    const ushort* __restrict__ OcumG, // [B][CJ] fp16
    unsigned* __restrict__ partial)   // [bid][bl 32][cjp 256] u32(h2)
{
    constexpr int NB = 4096 / NPB;                   // n-blocks per b-tile
    const int bid = blockIdx.x;
    const int bt = bid / NB, nblk = bid % NB;        // NB pow2 -> shifts
    const int n0 = nblk * NPB;
    const int t = threadIdx.x, l = t & 63, w = t >> 6;
    const int bl = l & 31, hi = l >> 5;
    const int b = bt * 32 + bl;

    __shared__ __align__(16) float pd[2][32][12];  // [buf][b][wave] e-partials
    __shared__ unsigned sep[8192];                 // 32KB epilogue staging

    const int cj0 = w * 64 + bl, cj1 = cj0 + 32;
    const float* xb = x + (size_t)b * 32768 + (size_t)n0 * 8 + hi * 4;
    const float* wb0 = W + (size_t)(cj0 >> 4) * 524288 + (size_t)n0 * 128 + (cj0 & 15) * 8 + hi * 4;
    const float* wb1 = W + (size_t)(cj1 >> 4) * 524288 + (size_t)n0 * 128 + (cj1 & 15) * 8 + hi * 4;
    ushort* whp0 = Wh + ((size_t)n0 * 512 + cj0) * 8 + hi * 4;
    ushort* whp1 = Wh + ((size_t)n0 * 512 + cj1) * 8 + hi * 4;

    h2 oc[2][8];
    if (!PASS0) {
        const unsigned* og = reinterpret_cast<const unsigned*>(OcumG);
        #pragma unroll
        for (int mt = 0; mt < 2; ++mt) {
            const int cA = 4 * w + 2 * mt;
            const unsigned idx = (unsigned)b * 256 + cA * 8 + hi * 2;
            oc[mt][0] = uash2(og[idx]);      oc[mt][1] = uash2(og[idx + 1]);
            oc[mt][2] = uash2(og[idx + 4]);  oc[mt][3] = uash2(og[idx + 5]);
            oc[mt][4] = uash2(og[idx + 8]);  oc[mt][5] = uash2(og[idx + 9]);
            oc[mt][6] = uash2(og[idx + 12]); oc[mt][7] = uash2(og[idx + 13]);
        }
    }

    f32x16 zero = {};
    f32x16 acc0 = {}, acc1 = {};

    if (PASS0) {
        float4 wv0 = *reinterpret_cast<const float4*>(wb0);
        float4 wv1 = *reinterpret_cast<const float4*>(wb1);
        float4 xv  = *reinterpret_cast<const float4*>(xb);
        #pragma unroll 1
        for (int s = 0; s < NPB; ++s) {
            float4 wv0n, wv1n, xvn;
            if (s < NPB - 1) {
                wv0n = *reinterpret_cast<const float4*>(wb0 + (s + 1) * 128);
                wv1n = *reinterpret_cast<const float4*>(wb1 + (s + 1) * 128);
                xvn  = *reinterpret_cast<const float4*>(xb + (s + 1) * 8);
            }
            half4 a0, a1, bf;
            a0[0] = (__fp16)wv0.x; a0[1] = (__fp16)wv0.y; a0[2] = (__fp16)wv0.z; a0[3] = (__fp16)wv0.w;
            a1[0] = (__fp16)wv1.x; a1[1] = (__fp16)wv1.y; a1[2] = (__fp16)wv1.z; a1[3] = (__fp16)wv1.w;
            bf[0] = (__fp16)xv.x;  bf[1] = (__fp16)xv.y;  bf[2] = (__fp16)xv.z;  bf[3] = (__fp16)xv.w;
            if (bt == 0) {  // fold W conversion into pass 0
                *reinterpret_cast<half4*>(whp0 + (size_t)s * 4096) = a0;
                *reinterpret_cast<half4*>(whp1 + (size_t)s * 4096) = a1;
            }
            acc0 = __builtin_amdgcn_mfma_f32_32x32x8f16(a0, bf, acc0, 0, 0, 0);
            acc1 = __builtin_amdgcn_mfma_f32_32x32x8f16(a1, bf, acc1, 0, 0, 0);
            wv0 = wv0n; wv1 = wv1n; xv = xvn;
        }
        #pragma unroll
        for (int r = 0; r < 16; ++r) { acc0[r] *= 0.03125f; acc1[r] *= 0.03125f; }
    } else {
        half4 a0 = *reinterpret_cast<const half4*>(whp0);
        half4 a1 = *reinterpret_cast<const half4*>(whp1);
        float4 xv = *reinterpret_cast<const float4*>(xb);
        #pragma unroll 1
        for (int s = 0; s < NPB; ++s) {
            half4 a0n, a1n; float4 xvn;
            if (s < NPB - 1) {
                a0n = *reinterpret_cast<const half4*>(whp0 + (size_t)(s + 1) * 4096);
                a1n = *reinterpret_cast<const half4*>(whp1 + (size_t)(s + 1) * 4096);
                xvn = *reinterpret_cast<const float4*>(xb + (s + 1) * 8);
            }
            half4 bf;
            bf[0] = (__fp16)xv.x; bf[1] = (__fp16)xv.y; bf[2] = (__fp16)xv.z; bf[3] = (__fp16)xv.w;
            f32x16 d0 = __builtin_amdgcn_mfma_f32_32x32x8f16(a0, bf, zero, 0, 0, 0);
            f32x16 d1 = __builtin_amdgcn_mfma_f32_32x32x8f16(a1, bf, zero, 0, 0, 0);
            // pack hat rows (j pairs) for coupling dots
            h2 h0[8], h1[8];
            #pragma unroll
            for (int q = 0; q < 8; ++q) {
                h0[q] = __builtin_amdgcn_cvt_pkrtz(d0[2 * q], d0[2 * q + 1]);
                h1[q] = __builtin_amdgcn_cvt_pkrtz(d1[2 * q], d1[2 * q + 1]);
            }
            // logits: this half-lane's 8 j's of each c; q0..3 -> cA, q4..7 -> cB
            float pA0 = fdot2(h0[3], oc[0][3], fdot2(h0[2], oc[0][2], fdot2(h0[1], oc[0][1], fdot2(h0[0], oc[0][0], 0.f))));
            float pB0 = fdot2(h0[7], oc[0][7], fdot2(h0[6], oc[0][6], fdot2(h0[5], oc[0][5], fdot2(h0[4], oc[0][4], 0.f))));
            float pA1 = fdot2(h1[3], oc[1][3], fdot2(h1[2], oc[1][2], fdot2(h1[1], oc[1][1], fdot2(h1[0], oc[1][0], 0.f))));
            float pB1 = fdot2(h1[7], oc[1][7], fdot2(h1[6], oc[1][6], fdot2(h1[5], oc[1][5], fdot2(h1[4], oc[1][4], 0.f))));
            pA0 += __shfl_xor(pA0, 32, 64);
            pB0 += __shfl_xor(pB0, 32, 64);
            pA1 += __shfl_xor(pA1, 32, 64);
            pB1 += __shfl_xor(pB1, 32, 64);
            float eA0 = __expf(pA0), eB0 = __expf(pB0), eA1 = __expf(pA1), eB1 = __expf(pB1);
            const int buf = s & 1;
            if (l < 32) pd[buf][bl][w] = eA0 + eB0 + eA1 + eB1;  // 4-c partial
            __syncthreads();
            const float4 q0 = *reinterpret_cast<const float4*>(&pd[buf][bl][0]);
            const float4 q1 = *reinterpret_cast<const float4*>(&pd[buf][bl][4]);
            const float rd = __builtin_amdgcn_rcpf(q0.x + q0.y + q0.z + q0.w +
                                                   q1.x + q1.y + q1.z + q1.w);
            const float cA0 = eA0 * rd, cB0 = eB0 * rd, cA1 = eA1 * rd, cB1 = eB1 * rd;
            #pragma unroll
            for (int r = 0; r < 8; ++r)  { acc0[r] += d0[r] * cA0; acc1[r] += d1[r] * cA1; }
            #pragma unroll
            for (int r = 8; r < 16; ++r) { acc0[r] += d0[r] * cB0; acc1[r] += d1[r] * cB1; }
            a0 = a0n; a1 = a1n; xv = xvn;
        }
    }

    // ---- epilogue: stage h2 partial tile in LDS (XOR-swizzled), copy out --
    __syncthreads();
    #pragma unroll
    for (int mt = 0; mt < 2; ++mt) {
        #pragma unroll
        for (int q = 0; q < 8; ++q) {
            const float e0 = mt ? acc1[2 * q] : acc0[2 * q];
            const float e1 = mt ? acc1[2 * q + 1] : acc0[2 * q + 1];
            U2 u; u.h = __builtin_amdgcn_cvt_pkrtz(e0, e1);
            const int cjp = w * 32 + mt * 16 + 4 * (q >> 1) + (q & 1) + 2 * hi;
            sep[bl * 256 + (cjp ^ bl)] = u.u;   // swizzle: conflict-free banks
        }
    }
    __syncthreads();
    const unsigned gbase = (unsigned)bid * 8192;
    #pragma unroll
    for (int u2 = 0; u2 < 16; ++u2) {
        const int idx = t + u2 * 512;
        const int ubl = idx >> 8, ucjp = idx & 255;
        partial[gbase + idx] = sep[ubl * 256 + (ucjp ^ ubl)];
    }
}

// ---- final reduce + squash + Ocum update ----------------------------------

template <int NB>
__global__ __launch_bounds__(256) void reduce_squash(const unsigned* __restrict__ partial32,
                                                     ushort* __restrict__ OcumG,
                                                     float* __restrict__ out,
                                                     int passIdx) {
    const int tid = blockIdx.x * 256 + threadIdx.x;  // 0..16383
    const int b = tid >> 8, cjp = tid & 255;
    const int bt = b >> 5, bl = b & 31;
    const unsigned base = (unsigned)bt * (unsigned)NB * 8192u + (unsigned)bl * 256u + (unsigned)cjp;
    float sx = 0.f, sy = 0.f;
    #pragma unroll 8
    for (int nb = 0; nb < NB; ++nb) {
        U2 v; v.u = partial32[base + nb * 8192];
        sx += (float)v.h.x;
        sy += (float)v.h.y;
    }
    float s2 = sx * sx + sy * sy;                    // 16 j live in 8 lanes
    s2 += __shfl_xor(s2, 1, 64);
    s2 += __shfl_xor(s2, 2, 64);
    s2 += __shfl_xor(s2, 4, 64);
    float scale = (s2 / (1.f + s2)) / sqrtf(s2 + 1e-7f);
    float o0 = scale * sx, o1 = scale * sy;

    unsigned* ocp = reinterpret_cast<unsigned*>(OcumG) + b * 256 + cjp;
    float a0 = o0, a1 = o1;
    if (passIdx) {
        U2 old; old.u = *ocp;
        a0 += (float)old.h.x;
        a1 += (float)old.h.y;
    }
    U2 nw; nw.h = __builtin_amdgcn_cvt_pkrtz(a0, a1);
    *ocp = nw.u;

    if (passIdx == 2) {
        out[b * 512 + cjp * 2] = o0;
        out[b * 512 + cjp * 2 + 1] = o1;
    }
}

// ---- host ------------------------------------------------------------------

extern "C" void kernel_launch(void* const* d_in, const int* in_sizes, int n_in,
                              void* d_out, int out_size, void* d_ws, size_t ws_size,
                              hipStream_t stream) {
    const float* x = (const float*)d_in[0];
    const float* W = (const float*)d_in[1];
    float* out = (float*)d_out;

    char* ws = (char*)d_ws;
    ushort* Wh = (ushort*)ws;                                        // 32 MiB

    const size_t MiB = 1024 * 1024;
    // NPB=16 layout needs 48 MiB + 64 KiB of workspace.
    if (ws_size >= 48 * MiB + 65536) {
        unsigned* partialU = (unsigned*)(ws + 32 * MiB);             // 16 MiB
        ushort* OcumG = (ushort*)(ws + 48 * MiB);                    // 64 KiB
        for (int pass = 0; pass < 3; ++pass) {
            if (pass == 0)
                fused_pass<1, 16><<<512, 512, 0, stream>>>(W, x, Wh, OcumG, partialU);
            else
                fused_pass<0, 16><<<512, 512, 0, stream>>>(W, x, Wh, OcumG, partialU);
            reduce_squash<256><<<64, 256, 0, stream>>>(partialU, OcumG, out, pass);
        }
    } else {
        // fallback: exact round-8 configuration (verified, 44.07 MiB)
        unsigned* partialU = (unsigned*)(ws + 32 * MiB);             // 8 MiB
        ushort* OcumG = (ushort*)(ws + 40 * MiB);                    // 64 KiB
        for (int pass = 0; pass < 3; ++pass) {
            if (pass == 0)
                fused_pass<1, 32><<<256, 512, 0, stream>>>(W, x, Wh, OcumG, partialU);
            else
                fused_pass<0, 32><<<256, 512, 0, stream>>>(W, x, Wh, OcumG, partialU);
            reduce_squash<128><<<64, 256, 0, stream>>>(partialU, OcumG, out, pass);
        }
    }
}

// Round 5
// 180.870 us; speedup vs baseline: 2.1683x; 1.1406x over previous
//
#include <hip/hip_runtime.h>
#include <math.h>

// CapsuleLayer dynamic routing — round 12 (= round 11 resubmit; container
// infra failed twice, no counters returned; kernel re-audited for OOB/align
// faults and found clean).
// B=64, N=4096, I=8, C=32, D=16, 3 routing iterations.
//
// Round-10 post-mortem: 2 blocks/CU gained only 3us -> not occupancy-bound.
// FETCH_SIZE across rounds shows W/Wh/x are L3-resident (fetch << input
// size) -> kernels are LLC-traffic/latency bound. Three fixes:
//  1) pass0 split by cj-half (not b-half): W read once grid-wide (134MB not
//     268MB of LLC traffic); every block stores a disjoint Wh slice.
//  2) pass0 also emits transposed xh[n][b][i] fp16 (4MiB): pass1/2 B-frag
//     loads become coalesced 16B/lane (were 64-way scattered f32 + 4 cvts
//     per step).
//  3) reduce_squash: 4 threads/output (grid 64->256 blocks), shfl combine;
//     per-thread serial loads 256->64.
// Pass1/2 verified core (MFMA map, softmax, epilogue swizzle) unchanged.
//
// ws (NPB=16): Wh fp16 [n][cj][i] 32 MiB | partial u32(h2) 16 MiB |
//              xh fp16 [n][b][i] 4 MiB | OcumG fp16 [b][cj] 64 KiB (52.07)

typedef __fp16 h2 __attribute__((ext_vector_type(2)));
typedef __fp16 half4 __attribute__((ext_vector_type(4)));
typedef float f32x16 __attribute__((ext_vector_type(16)));

union U2 { h2 h; unsigned u; };

__device__ __forceinline__ float fdot2(h2 a, h2 b, float c) {
    return __builtin_amdgcn_fdot2(a, b, c, false);
}
__device__ __forceinline__ h2 uash2(unsigned u) { U2 t; t.u = u; return t.h; }

// ---- pass 0: uniform coupling; cj-split; emits Wh and xh ------------------

template <int NPB>
__global__ __launch_bounds__(512, 4) void pass0_kernel(
    const float* __restrict__ W,      // [C][N][D][I] f32
    const float* __restrict__ x,      // [B][N][I] f32
    ushort* __restrict__ Wh,          // [N][CJ][I] fp16
    ushort* __restrict__ xh,          // [N][B][I] fp16
    unsigned* __restrict__ partial)   // [(bt*NB+nblk)][bl 32][cjp 256] u32(h2)
{
    constexpr int NB = 4096 / NPB;
    const int bid = blockIdx.x;
    const int half = bid / NB, nblk = bid % NB;      // XCD = bid%8 = nblk%8
    const int n0 = nblk * NPB;
    const int t = threadIdx.x, l = t & 63, w = t >> 6;
    const int bl = l & 31, hi = l >> 5;
    const int cj = half * 256 + w * 32 + bl;         // this lane's A-row

    __shared__ unsigned sep[8192];                   // 32KB epilogue staging

    const float* wb  = W + (size_t)(cj >> 4) * 524288 + (size_t)n0 * 128 + (cj & 15) * 8 + hi * 4;
    const float* xb0 = x + (size_t)bl * 32768 + (size_t)n0 * 8 + hi * 4;
    const float* xb1 = x + (size_t)(bl + 32) * 32768 + (size_t)n0 * 8 + hi * 4;
    ushort* whp = Wh + ((size_t)n0 * 512 + cj) * 8 + hi * 4;
    ushort* xhp = xh + ((size_t)n0 * 64 + bl) * 8 + hi * 4;

    f32x16 acc0 = {}, acc1 = {};                     // b 0-31 / b 32-63
    float4 wv  = *reinterpret_cast<const float4*>(wb);
    float4 xv0 = *reinterpret_cast<const float4*>(xb0);
    float4 xv1 = *reinterpret_cast<const float4*>(xb1);
    #pragma unroll 1
    for (int s = 0; s < NPB; ++s) {
        float4 wvn, x0n, x1n;
        if (s < NPB - 1) {
            wvn = *reinterpret_cast<const float4*>(wb + (s + 1) * 128);
            x0n = *reinterpret_cast<const float4*>(xb0 + (s + 1) * 8);
            x1n = *reinterpret_cast<const float4*>(xb1 + (s + 1) * 8);
        }
        half4 a, b0, b1;
        a[0] = (__fp16)wv.x;  a[1] = (__fp16)wv.y;  a[2] = (__fp16)wv.z;  a[3] = (__fp16)wv.w;
        b0[0] = (__fp16)xv0.x; b0[1] = (__fp16)xv0.y; b0[2] = (__fp16)xv0.z; b0[3] = (__fp16)xv0.w;
        b1[0] = (__fp16)xv1.x; b1[1] = (__fp16)xv1.y; b1[2] = (__fp16)xv1.z; b1[3] = (__fp16)xv1.w;
        *reinterpret_cast<half4*>(whp + (size_t)s * 4096) = a;
        if (w == 0) {                                // x identical across waves
            *reinterpret_cast<half4*>(xhp + (size_t)s * 512) = b0;
            *reinterpret_cast<half4*>(xhp + (size_t)s * 512 + 256) = b1;
        }
        acc0 = __builtin_amdgcn_mfma_f32_32x32x8f16(a, b0, acc0, 0, 0, 0);
        acc1 = __builtin_amdgcn_mfma_f32_32x32x8f16(a, b1, acc1, 0, 0, 0);
        wv = wvn; xv0 = x0n; xv1 = x1n;
    }
    #pragma unroll
    for (int r = 0; r < 16; ++r) { acc0[r] *= 0.03125f; acc1[r] *= 0.03125f; }

    // epilogue: sep[b 64][cjp_local 128], XOR-swizzled by b
    #pragma unroll
    for (int hb = 0; hb < 2; ++hb) {
        #pragma unroll
        for (int q = 0; q < 8; ++q) {
            const float e0 = hb ? acc1[2 * q] : acc0[2 * q];
            const float e1 = hb ? acc1[2 * q + 1] : acc0[2 * q + 1];
            U2 u; u.h = __builtin_amdgcn_cvt_pkrtz(e0, e1);
            const int cjp = w * 16 + 4 * (q >> 1) + (q & 1) + 2 * hi;  // local
            const int bb = bl + 32 * hb;
            sep[bb * 128 + (cjp ^ bb)] = u.u;
        }
    }
    __syncthreads();
    #pragma unroll
    for (int u2 = 0; u2 < 16; ++u2) {
        const int idx = t + u2 * 512;                // 0..8191
        const int ub = idx >> 7, ucjp = idx & 127;
        partial[(size_t)((ub >> 5) * NB + nblk) * 8192 + (ub & 31) * 256 + half * 128 + ucjp]
            = sep[ub * 128 + (ucjp ^ ub)];
    }
}

// ---- pass 1/2: softmax coupling (b-split, verified round-8 core) ----------

template <int NPB>
__global__ __launch_bounds__(512, 4) void pass12_kernel(
    const ushort* __restrict__ Wh,    // [N][CJ][I] fp16
    const ushort* __restrict__ xh,    // [N][B][I] fp16
    const ushort* __restrict__ OcumG, // [B][CJ] fp16
    unsigned* __restrict__ partial)   // [bid][bl 32][cjp 256] u32(h2)
{
    constexpr int NB = 4096 / NPB;
    const int bid = blockIdx.x;
    const int bt = bid / NB, nblk = bid % NB;
    const int n0 = nblk * NPB;
    const int t = threadIdx.x, l = t & 63, w = t >> 6;
    const int bl = l & 31, hi = l >> 5;
    const int b = bt * 32 + bl;

    __shared__ __align__(16) float pd[2][32][12];  // [buf][b][wave] e-partials
    __shared__ unsigned sep[8192];                 // 32KB epilogue staging

    const int cj0 = w * 64 + bl, cj1 = cj0 + 32;
    const ushort* xb = xh + ((size_t)n0 * 64 + b) * 8 + hi * 4;
    const ushort* whp0 = Wh + ((size_t)n0 * 512 + cj0) * 8 + hi * 4;
    const ushort* whp1 = Wh + ((size_t)n0 * 512 + cj1) * 8 + hi * 4;

    h2 oc[2][8];
    {
        const unsigned* og = reinterpret_cast<const unsigned*>(OcumG);
        #pragma unroll
        for (int mt = 0; mt < 2; ++mt) {
            const int cA = 4 * w + 2 * mt;
            const unsigned idx = (unsigned)b * 256 + cA * 8 + hi * 2;
            oc[mt][0] = uash2(og[idx]);      oc[mt][1] = uash2(og[idx + 1]);
            oc[mt][2] = uash2(og[idx + 4]);  oc[mt][3] = uash2(og[idx + 5]);
            oc[mt][4] = uash2(og[idx + 8]);  oc[mt][5] = uash2(og[idx + 9]);
            oc[mt][6] = uash2(og[idx + 12]); oc[mt][7] = uash2(og[idx + 13]);
        }
    }

    f32x16 zero = {};
    f32x16 acc0 = {}, acc1 = {};

    half4 a0 = *reinterpret_cast<const half4*>(whp0);
    half4 a1 = *reinterpret_cast<const half4*>(whp1);
    half4 bf = *reinterpret_cast<const half4*>(xb);
    #pragma unroll 1
    for (int s = 0; s < NPB; ++s) {
        half4 a0n, a1n, bfn;
        if (s < NPB - 1) {
            a0n = *reinterpret_cast<const half4*>(whp0 + (size_t)(s + 1) * 4096);
            a1n = *reinterpret_cast<const half4*>(whp1 + (size_t)(s + 1) * 4096);
            bfn = *reinterpret_cast<const half4*>(xb + (size_t)(s + 1) * 512);
        }
        f32x16 d0 = __builtin_amdgcn_mfma_f32_32x32x8f16(a0, bf, zero, 0, 0, 0);
        f32x16 d1 = __builtin_amdgcn_mfma_f32_32x32x8f16(a1, bf, zero, 0, 0, 0);
        // pack hat rows (j pairs) for coupling dots
        h2 h0[8], h1[8];
        #pragma unroll
        for (int q = 0; q < 8; ++q) {
            h0[q] = __builtin_amdgcn_cvt_pkrtz(d0[2 * q], d0[2 * q + 1]);
            h1[q] = __builtin_amdgcn_cvt_pkrtz(d1[2 * q], d1[2 * q + 1]);
        }
        // logits: this half-lane's 8 j's of each c; q0..3 -> cA, q4..7 -> cB
        float pA0 = fdot2(h0[3], oc[0][3], fdot2(h0[2], oc[0][2], fdot2(h0[1], oc[0][1], fdot2(h0[0], oc[0][0], 0.f))));
        float pB0 = fdot2(h0[7], oc[0][7], fdot2(h0[6], oc[0][6], fdot2(h0[5], oc[0][5], fdot2(h0[4], oc[0][4], 0.f))));
        float pA1 = fdot2(h1[3], oc[1][3], fdot2(h1[2], oc[1][2], fdot2(h1[1], oc[1][1], fdot2(h1[0], oc[1][0], 0.f))));
        float pB1 = fdot2(h1[7], oc[1][7], fdot2(h1[6], oc[1][6], fdot2(h1[5], oc[1][5], fdot2(h1[4], oc[1][4], 0.f))));
        pA0 += __shfl_xor(pA0, 32, 64);
        pB0 += __shfl_xor(pB0, 32, 64);
        pA1 += __shfl_xor(pA1, 32, 64);
        pB1 += __shfl_xor(pB1, 32, 64);
        float eA0 = __expf(pA0), eB0 = __expf(pB0), eA1 = __expf(pA1), eB1 = __expf(pB1);
        const int buf = s & 1;
        if (l < 32) pd[buf][bl][w] = eA0 + eB0 + eA1 + eB1;  // 4-c partial
        __syncthreads();
        const float4 q0 = *reinterpret_cast<const float4*>(&pd[buf][bl][0]);
        const float4 q1 = *reinterpret_cast<const float4*>(&pd[buf][bl][4]);
        const float rd = __builtin_amdgcn_rcpf(q0.x + q0.y + q0.z + q0.w +
                                               q1.x + q1.y + q1.z + q1.w);
        const float cA0 = eA0 * rd, cB0 = eB0 * rd, cA1 = eA1 * rd, cB1 = eB1 * rd;
        #pragma unroll
        for (int r = 0; r < 8; ++r)  { acc0[r] += d0[r] * cA0; acc1[r] += d1[r] * cA1; }
        #pragma unroll
        for (int r = 8; r < 16; ++r) { acc0[r] += d0[r] * cB0; acc1[r] += d1[r] * cB1; }
        a0 = a0n; a1 = a1n; bf = bfn;
    }

    // ---- epilogue: stage h2 partial tile in LDS (XOR-swizzled), copy out --
    __syncthreads();
    #pragma unroll
    for (int mt = 0; mt < 2; ++mt) {
        #pragma unroll
        for (int q = 0; q < 8; ++q) {
            const float e0 = mt ? acc1[2 * q] : acc0[2 * q];
            const float e1 = mt ? acc1[2 * q + 1] : acc0[2 * q + 1];
            U2 u; u.h = __builtin_amdgcn_cvt_pkrtz(e0, e1);
            const int cjp = w * 32 + mt * 16 + 4 * (q >> 1) + (q & 1) + 2 * hi;
            sep[bl * 256 + (cjp ^ bl)] = u.u;   // swizzle: conflict-free banks
        }
    }
    __syncthreads();
    const unsigned gbase = (unsigned)bid * 8192;
    #pragma unroll
    for (int u2 = 0; u2 < 16; ++u2) {
        const int idx = t + u2 * 512;
        const int ubl = idx >> 8, ucjp = idx & 255;
        partial[gbase + idx] = sep[ubl * 256 + (ucjp ^ ubl)];
    }
}

// ---- final reduce + squash + Ocum update (4 threads per output) -----------

template <int NB>
__global__ __launch_bounds__(256) void reduce_squash(const unsigned* __restrict__ partial32,
                                                     ushort* __restrict__ OcumG,
                                                     float* __restrict__ out,
                                                     int passIdx) {
    const int gtid = blockIdx.x * 256 + threadIdx.x;  // 0..65535
    const int oid = gtid >> 2, sub = gtid & 3;
    const int b = oid >> 8, cjp = oid & 255;
    const int bt = b >> 5, bl = b & 31;
    const unsigned base = (unsigned)bt * (unsigned)NB * 8192u + (unsigned)bl * 256u + (unsigned)cjp;
    float sx = 0.f, sy = 0.f;
    #pragma unroll 8
    for (int i = 0; i < NB / 4; ++i) {
        U2 v; v.u = partial32[base + (unsigned)(sub + 4 * i) * 8192u];
        sx += (float)v.h.x;
        sy += (float)v.h.y;
    }
    sx += __shfl_xor(sx, 1, 64); sy += __shfl_xor(sy, 1, 64);
    sx += __shfl_xor(sx, 2, 64); sy += __shfl_xor(sy, 2, 64);
    float s2 = sx * sx + sy * sy;                    // sum over capsule's 8 cjp
    s2 += __shfl_xor(s2, 4, 64);
    s2 += __shfl_xor(s2, 8, 64);
    s2 += __shfl_xor(s2, 16, 64);
    float scale = (s2 / (1.f + s2)) / sqrtf(s2 + 1e-7f);
    float o0 = scale * sx, o1 = scale * sy;

    if (sub == 0) {
        unsigned* ocp = reinterpret_cast<unsigned*>(OcumG) + b * 256 + cjp;
        float a0 = o0, a1 = o1;
        if (passIdx) {
            U2 old; old.u = *ocp;
            a0 += (float)old.h.x;
            a1 += (float)old.h.y;
        }
        U2 nw; nw.h = __builtin_amdgcn_cvt_pkrtz(a0, a1);
        *ocp = nw.u;
        if (passIdx == 2) {
            out[b * 512 + cjp * 2] = o0;
            out[b * 512 + cjp * 2 + 1] = o1;
        }
    }
}

// ---- host ------------------------------------------------------------------

extern "C" void kernel_launch(void* const* d_in, const int* in_sizes, int n_in,
                              void* d_out, int out_size, void* d_ws, size_t ws_size,
                              hipStream_t stream) {
    const float* x = (const float*)d_in[0];
    const float* W = (const float*)d_in[1];
    float* out = (float*)d_out;

    char* ws = (char*)d_ws;
    ushort* Wh = (ushort*)ws;                                        // 32 MiB
    const size_t MiB = 1024 * 1024;

    if (ws_size >= 52 * MiB + 65536) {
        // NPB=16: partial 16 MiB | xh 4 MiB | Ocum 64 KiB
        unsigned* partialU = (unsigned*)(ws + 32 * MiB);
        ushort* xh = (ushort*)(ws + 48 * MiB);
        ushort* OcumG = (ushort*)(ws + 52 * MiB);
        pass0_kernel<16><<<512, 512, 0, stream>>>(W, x, Wh, xh, partialU);
        reduce_squash<256><<<256, 256, 0, stream>>>(partialU, OcumG, out, 0);
        pass12_kernel<16><<<512, 512, 0, stream>>>(Wh, xh, OcumG, partialU);
        reduce_squash<256><<<256, 256, 0, stream>>>(partialU, OcumG, out, 1);
        pass12_kernel<16><<<512, 512, 0, stream>>>(Wh, xh, OcumG, partialU);
        reduce_squash<256><<<256, 256, 0, stream>>>(partialU, OcumG, out, 2);
    } else {
        // fallback NPB=32: partial 8 MiB | xh 4 MiB | Ocum 64 KiB (44.07 MiB)
        unsigned* partialU = (unsigned*)(ws + 32 * MiB);
        ushort* xh = (ushort*)(ws + 40 * MiB);
        ushort* OcumG = (ushort*)(ws + 44 * MiB);
        pass0_kernel<32><<<256, 512, 0, stream>>>(W, x, Wh, xh, partialU);
        reduce_squash<128><<<256, 256, 0, stream>>>(partialU, OcumG, out, 0);
        pass12_kernel<32><<<256, 512, 0, stream>>>(Wh, xh, OcumG, partialU);
        reduce_squash<128><<<256, 256, 0, stream>>>(partialU, OcumG, out, 1);
        pass12_kernel<32><<<256, 512, 0, stream>>>(Wh, xh, OcumG, partialU);
        reduce_squash<128><<<256, 256, 0, stream>>>(partialU, OcumG, out, 2);
    }
}

// Round 6
// 170.806 us; speedup vs baseline: 2.2960x; 1.0589x over previous
//
#include <hip/hip_runtime.h>
#include <math.h>

// CapsuleLayer dynamic routing — round 13.
// B=64, N=4096, I=8, C=32, D=16, 3 routing iterations.
//
// Round-12 post-mortem: pass0 stuck at 41.6us across W-traffic halving ->
// not BW-bound. Cause: x loads give each lane a different b row (128KB
// stride) = 2x64 distinct cache lines/iter/wave of TA address pressure +
// uncovered latency (same pathology the xh fix removed from pass12).
// Round 13 (one change): pass0 stages the x tile through LDS --
// coalesced f32 reads (lanes sweep n,i per b row) -> cvt fp16 -> swizzled
// LDS xs[n][b][i] -> inner loop B-frags via ds_read_b64; xh emitted
// coalesced from LDS by half==0 blocks only. pass12/reduce verbatim.
//
// ws (NPB=16): Wh fp16 [n][cj][i] 32 MiB | partial u32(h2) 16 MiB |
//              xh fp16 [n][b][i] 4 MiB | OcumG fp16 [b][cj] 64 KiB (52.07)

typedef __fp16 h2 __attribute__((ext_vector_type(2)));
typedef __fp16 half4 __attribute__((ext_vector_type(4)));
typedef float f32x16 __attribute__((ext_vector_type(16)));

union U2 { h2 h; unsigned u; };

__device__ __forceinline__ float fdot2(h2 a, h2 b, float c) {
    return __builtin_amdgcn_fdot2(a, b, c, false);
}
__device__ __forceinline__ h2 uash2(unsigned u) { U2 t; t.u = u; return t.h; }

// ---- pass 0: uniform coupling; cj-split; LDS-staged x; emits Wh and xh ----

template <int NPB>
__global__ __launch_bounds__(512, 4) void pass0_kernel(
    const float* __restrict__ W,      // [C][N][D][I] f32
    const float* __restrict__ x,      // [B][N][I] f32
    ushort* __restrict__ Wh,          // [N][CJ][I] fp16
    ushort* __restrict__ xh,          // [N][B][I] fp16
    unsigned* __restrict__ partial)   // [(bt*NB+nblk)][bl 32][cjp 256] u32(h2)
{
    constexpr int NB = 4096 / NPB;
    const int bid = blockIdx.x;
    const int half = bid / NB, nblk = bid % NB;      // XCD = bid%8 = nblk%8
    const int n0 = nblk * NPB;
    const int t = threadIdx.x, l = t & 63, w = t >> 6;
    const int bl = l & 31, hi = l >> 5;
    const int cj = half * 256 + w * 32 + bl;         // this lane's A-row

    __shared__ __align__(16) ushort xs[NPB * 512];   // [n][b][i] fp16, swizzled
    __shared__ unsigned sep[8192];                   // 32KB epilogue staging

    // ---- stage x tile: coalesced f32 read -> fp16 -> swizzled LDS --------
    #pragma unroll
    for (int rep = 0; rep < NPB / 4; ++rep) {
        const int idx = t + rep * 512;               // float4 id, 0..NPB*128-1
        const int b = idx / (2 * NPB), f4 = idx % (2 * NPB);
        const int nl = f4 >> 1, isl = f4 & 1;
        float4 v = *reinterpret_cast<const float4*>(
            x + (size_t)b * 32768 + (size_t)n0 * 8 + f4 * 4);
        half4 h;
        h[0] = (__fp16)v.x; h[1] = (__fp16)v.y; h[2] = (__fp16)v.z; h[3] = (__fp16)v.w;
        const int slot = (nl * 128 + b * 2 + isl) ^ ((nl & 7) << 1) ^ ((b >> 3) & 3);
        *reinterpret_cast<half4*>(xs + slot * 4) = h;
    }
    __syncthreads();

    // ---- emit xh coalesced from LDS (half==0 blocks only) ----------------
    if (half == 0) {
        #pragma unroll
        for (int rep = 0; rep < NPB / 4; ++rep) {
            const int u = t + rep * 512;             // half4 id
            const int nl = u >> 7, b = (u >> 1) & 63, isl = u & 1;
            const int slot = (nl * 128 + b * 2 + isl) ^ ((nl & 7) << 1) ^ ((b >> 3) & 3);
            half4 h = *reinterpret_cast<const half4*>(xs + slot * 4);
            *reinterpret_cast<half4*>(xh + (size_t)n0 * 512 + u * 4) = h;
        }
    }

    const float* wb = W + (size_t)(cj >> 4) * 524288 + (size_t)n0 * 128 + (cj & 15) * 8 + hi * 4;
    ushort* whp = Wh + ((size_t)n0 * 512 + cj) * 8 + hi * 4;

    f32x16 acc0 = {}, acc1 = {};                     // b 0-31 / b 32-63
    float4 wv = *reinterpret_cast<const float4*>(wb);
    #pragma unroll 1
    for (int s = 0; s < NPB; ++s) {
        float4 wvn;
        if (s < NPB - 1)
            wvn = *reinterpret_cast<const float4*>(wb + (s + 1) * 128);
        const int sw = ((s & 7) << 1) ^ ((bl >> 3) & 3);
        const int slot0 = (s * 128 + bl * 2 + hi) ^ sw;
        const int slot1 = (s * 128 + bl * 2 + 64 + hi) ^ sw;
        half4 b0 = *reinterpret_cast<const half4*>(xs + slot0 * 4);
        half4 b1 = *reinterpret_cast<const half4*>(xs + slot1 * 4);
        half4 a;
        a[0] = (__fp16)wv.x; a[1] = (__fp16)wv.y; a[2] = (__fp16)wv.z; a[3] = (__fp16)wv.w;
        *reinterpret_cast<half4*>(whp + (size_t)s * 4096) = a;
        acc0 = __builtin_amdgcn_mfma_f32_32x32x8f16(a, b0, acc0, 0, 0, 0);
        acc1 = __builtin_amdgcn_mfma_f32_32x32x8f16(a, b1, acc1, 0, 0, 0);
        wv = wvn;
    }
    #pragma unroll
    for (int r = 0; r < 16; ++r) { acc0[r] *= 0.03125f; acc1[r] *= 0.03125f; }

    // epilogue: sep[b 64][cjp_local 128], XOR-swizzled by b
    #pragma unroll
    for (int hb = 0; hb < 2; ++hb) {
        #pragma unroll
        for (int q = 0; q < 8; ++q) {
            const float e0 = hb ? acc1[2 * q] : acc0[2 * q];
            const float e1 = hb ? acc1[2 * q + 1] : acc0[2 * q + 1];
            U2 u; u.h = __builtin_amdgcn_cvt_pkrtz(e0, e1);
            const int cjp = w * 16 + 4 * (q >> 1) + (q & 1) + 2 * hi;  // local
            const int bb = bl + 32 * hb;
            sep[bb * 128 + (cjp ^ bb)] = u.u;
        }
    }
    __syncthreads();
    #pragma unroll
    for (int u2 = 0; u2 < 16; ++u2) {
        const int idx = t + u2 * 512;                // 0..8191
        const int ub = idx >> 7, ucjp = idx & 127;
        partial[(size_t)((ub >> 5) * NB + nblk) * 8192 + (ub & 31) * 256 + half * 128 + ucjp]
            = sep[ub * 128 + (ucjp ^ ub)];
    }
}

// ---- pass 1/2: softmax coupling (b-split, verified round-8 core) ----------

template <int NPB>
__global__ __launch_bounds__(512, 4) void pass12_kernel(
    const ushort* __restrict__ Wh,    // [N][CJ][I] fp16
    const ushort* __restrict__ xh,    // [N][B][I] fp16
    const ushort* __restrict__ OcumG, // [B][CJ] fp16
    unsigned* __restrict__ partial)   // [bid][bl 32][cjp 256] u32(h2)
{
    constexpr int NB = 4096 / NPB;
    const int bid = blockIdx.x;
    const int bt = bid / NB, nblk = bid % NB;
    const int n0 = nblk * NPB;
    const int t = threadIdx.x, l = t & 63, w = t >> 6;
    const int bl = l & 31, hi = l >> 5;
    const int b = bt * 32 + bl;

    __shared__ __align__(16) float pd[2][32][12];  // [buf][b][wave] e-partials
    __shared__ unsigned sep[8192];                 // 32KB epilogue staging

    const int cj0 = w * 64 + bl, cj1 = cj0 + 32;
    const ushort* xb = xh + ((size_t)n0 * 64 + b) * 8 + hi * 4;
    const ushort* whp0 = Wh + ((size_t)n0 * 512 + cj0) * 8 + hi * 4;
    const ushort* whp1 = Wh + ((size_t)n0 * 512 + cj1) * 8 + hi * 4;

    h2 oc[2][8];
    {
        const unsigned* og = reinterpret_cast<const unsigned*>(OcumG);
        #pragma unroll
        for (int mt = 0; mt < 2; ++mt) {
            const int cA = 4 * w + 2 * mt;
            const unsigned idx = (unsigned)b * 256 + cA * 8 + hi * 2;
            oc[mt][0] = uash2(og[idx]);      oc[mt][1] = uash2(og[idx + 1]);
            oc[mt][2] = uash2(og[idx + 4]);  oc[mt][3] = uash2(og[idx + 5]);
            oc[mt][4] = uash2(og[idx + 8]);  oc[mt][5] = uash2(og[idx + 9]);
            oc[mt][6] = uash2(og[idx + 12]); oc[mt][7] = uash2(og[idx + 13]);
        }
    }

    f32x16 zero = {};
    f32x16 acc0 = {}, acc1 = {};

    half4 a0 = *reinterpret_cast<const half4*>(whp0);
    half4 a1 = *reinterpret_cast<const half4*>(whp1);
    half4 bf = *reinterpret_cast<const half4*>(xb);
    #pragma unroll 1
    for (int s = 0; s < NPB; ++s) {
        half4 a0n, a1n, bfn;
        if (s < NPB - 1) {
            a0n = *reinterpret_cast<const half4*>(whp0 + (size_t)(s + 1) * 4096);
            a1n = *reinterpret_cast<const half4*>(whp1 + (size_t)(s + 1) * 4096);
            bfn = *reinterpret_cast<const half4*>(xb + (size_t)(s + 1) * 512);
        }
        f32x16 d0 = __builtin_amdgcn_mfma_f32_32x32x8f16(a0, bf, zero, 0, 0, 0);
        f32x16 d1 = __builtin_amdgcn_mfma_f32_32x32x8f16(a1, bf, zero, 0, 0, 0);
        // pack hat rows (j pairs) for coupling dots
        h2 h0[8], h1[8];
        #pragma unroll
        for (int q = 0; q < 8; ++q) {
            h0[q] = __builtin_amdgcn_cvt_pkrtz(d0[2 * q], d0[2 * q + 1]);
            h1[q] = __builtin_amdgcn_cvt_pkrtz(d1[2 * q], d1[2 * q + 1]);
        }
        // logits: this half-lane's 8 j's of each c; q0..3 -> cA, q4..7 -> cB
        float pA0 = fdot2(h0[3], oc[0][3], fdot2(h0[2], oc[0][2], fdot2(h0[1], oc[0][1], fdot2(h0[0], oc[0][0], 0.f))));
        float pB0 = fdot2(h0[7], oc[0][7], fdot2(h0[6], oc[0][6], fdot2(h0[5], oc[0][5], fdot2(h0[4], oc[0][4], 0.f))));
        float pA1 = fdot2(h1[3], oc[1][3], fdot2(h1[2], oc[1][2], fdot2(h1[1], oc[1][1], fdot2(h1[0], oc[1][0], 0.f))));
        float pB1 = fdot2(h1[7], oc[1][7], fdot2(h1[6], oc[1][6], fdot2(h1[5], oc[1][5], fdot2(h1[4], oc[1][4], 0.f))));
        pA0 += __shfl_xor(pA0, 32, 64);
        pB0 += __shfl_xor(pB0, 32, 64);
        pA1 += __shfl_xor(pA1, 32, 64);
        pB1 += __shfl_xor(pB1, 32, 64);
        float eA0 = __expf(pA0), eB0 = __expf(pB0), eA1 = __expf(pA1), eB1 = __expf(pB1);
        const int buf = s & 1;
        if (l < 32) pd[buf][bl][w] = eA0 + eB0 + eA1 + eB1;  // 4-c partial
        __syncthreads();
        const float4 q0 = *reinterpret_cast<const float4*>(&pd[buf][bl][0]);
        const float4 q1 = *reinterpret_cast<const float4*>(&pd[buf][bl][4]);
        const float rd = __builtin_amdgcn_rcpf(q0.x + q0.y + q0.z + q0.w +
                                               q1.x + q1.y + q1.z + q1.w);
        const float cA0 = eA0 * rd, cB0 = eB0 * rd, cA1 = eA1 * rd, cB1 = eB1 * rd;
        #pragma unroll
        for (int r = 0; r < 8; ++r)  { acc0[r] += d0[r] * cA0; acc1[r] += d1[r] * cA1; }
        #pragma unroll
        for (int r = 8; r < 16; ++r) { acc0[r] += d0[r] * cB0; acc1[r] += d1[r] * cB1; }
        a0 = a0n; a1 = a1n; bf = bfn;
    }

    // ---- epilogue: stage h2 partial tile in LDS (XOR-swizzled), copy out --
    __syncthreads();
    #pragma unroll
    for (int mt = 0; mt < 2; ++mt) {
        #pragma unroll
        for (int q = 0; q < 8; ++q) {
            const float e0 = mt ? acc1[2 * q] : acc0[2 * q];
            const float e1 = mt ? acc1[2 * q + 1] : acc0[2 * q + 1];
            U2 u; u.h = __builtin_amdgcn_cvt_pkrtz(e0, e1);
            const int cjp = w * 32 + mt * 16 + 4 * (q >> 1) + (q & 1) + 2 * hi;
            sep[bl * 256 + (cjp ^ bl)] = u.u;   // swizzle: conflict-free banks
        }
    }
    __syncthreads();
    const unsigned gbase = (unsigned)bid * 8192;
    #pragma unroll
    for (int u2 = 0; u2 < 16; ++u2) {
        const int idx = t + u2 * 512;
        const int ubl = idx >> 8, ucjp = idx & 255;
        partial[gbase + idx] = sep[ubl * 256 + (ucjp ^ ubl)];
    }
}

// ---- final reduce + squash + Ocum update (4 threads per output) -----------

template <int NB>
__global__ __launch_bounds__(256) void reduce_squash(const unsigned* __restrict__ partial32,
                                                     ushort* __restrict__ OcumG,
                                                     float* __restrict__ out,
                                                     int passIdx) {
    const int gtid = blockIdx.x * 256 + threadIdx.x;  // 0..65535
    const int oid = gtid >> 2, sub = gtid & 3;
    const int b = oid >> 8, cjp = oid & 255;
    const int bt = b >> 5, bl = b & 31;
    const unsigned base = (unsigned)bt * (unsigned)NB * 8192u + (unsigned)bl * 256u + (unsigned)cjp;
    float sx = 0.f, sy = 0.f;
    #pragma unroll 8
    for (int i = 0; i < NB / 4; ++i) {
        U2 v; v.u = partial32[base + (unsigned)(sub + 4 * i) * 8192u];
        sx += (float)v.h.x;
        sy += (float)v.h.y;
    }
    sx += __shfl_xor(sx, 1, 64); sy += __shfl_xor(sy, 1, 64);
    sx += __shfl_xor(sx, 2, 64); sy += __shfl_xor(sy, 2, 64);
    float s2 = sx * sx + sy * sy;                    // sum over capsule's 8 cjp
    s2 += __shfl_xor(s2, 4, 64);
    s2 += __shfl_xor(s2, 8, 64);
    s2 += __shfl_xor(s2, 16, 64);
    float scale = (s2 / (1.f + s2)) / sqrtf(s2 + 1e-7f);
    float o0 = scale * sx, o1 = scale * sy;

    if (sub == 0) {
        unsigned* ocp = reinterpret_cast<unsigned*>(OcumG) + b * 256 + cjp;
        float a0 = o0, a1 = o1;
        if (passIdx) {
            U2 old; old.u = *ocp;
            a0 += (float)old.h.x;
            a1 += (float)old.h.y;
        }
        U2 nw; nw.h = __builtin_amdgcn_cvt_pkrtz(a0, a1);
        *ocp = nw.u;
        if (passIdx == 2) {
            out[b * 512 + cjp * 2] = o0;
            out[b * 512 + cjp * 2 + 1] = o1;
        }
    }
}

// ---- host ------------------------------------------------------------------

extern "C" void kernel_launch(void* const* d_in, const int* in_sizes, int n_in,
                              void* d_out, int out_size, void* d_ws, size_t ws_size,
                              hipStream_t stream) {
    const float* x = (const float*)d_in[0];
    const float* W = (const float*)d_in[1];
    float* out = (float*)d_out;

    char* ws = (char*)d_ws;
    ushort* Wh = (ushort*)ws;                                        // 32 MiB
    const size_t MiB = 1024 * 1024;

    if (ws_size >= 52 * MiB + 65536) {
        // NPB=16: partial 16 MiB | xh 4 MiB | Ocum 64 KiB
        unsigned* partialU = (unsigned*)(ws + 32 * MiB);
        ushort* xh = (ushort*)(ws + 48 * MiB);
        ushort* OcumG = (ushort*)(ws + 52 * MiB);
        pass0_kernel<16><<<512, 512, 0, stream>>>(W, x, Wh, xh, partialU);
        reduce_squash<256><<<256, 256, 0, stream>>>(partialU, OcumG, out, 0);
        pass12_kernel<16><<<512, 512, 0, stream>>>(Wh, xh, OcumG, partialU);
        reduce_squash<256><<<256, 256, 0, stream>>>(partialU, OcumG, out, 1);
        pass12_kernel<16><<<512, 512, 0, stream>>>(Wh, xh, OcumG, partialU);
        reduce_squash<256><<<256, 256, 0, stream>>>(partialU, OcumG, out, 2);
    } else {
        // fallback NPB=32: partial 8 MiB | xh 4 MiB | Ocum 64 KiB (44.07 MiB)
        unsigned* partialU = (unsigned*)(ws + 32 * MiB);
        ushort* xh = (ushort*)(ws + 40 * MiB);
        ushort* OcumG = (ushort*)(ws + 44 * MiB);
        pass0_kernel<32><<<256, 512, 0, stream>>>(W, x, Wh, xh, partialU);
        reduce_squash<128><<<256, 256, 0, stream>>>(partialU, OcumG, out, 0);
        pass12_kernel<32><<<256, 512, 0, stream>>>(Wh, xh, OcumG, partialU);
        reduce_squash<128><<<256, 256, 0, stream>>>(partialU, OcumG, out, 1);
        pass12_kernel<32><<<256, 512, 0, stream>>>(Wh, xh, OcumG, partialU);
        reduce_squash<128><<<256, 256, 0, stream>>>(partialU, OcumG, out, 2);
    }
}

// Round 7
// 167.615 us; speedup vs baseline: 2.3397x; 1.0190x over previous
//
#include <hip/hip_runtime.h>
#include <math.h>

// CapsuleLayer dynamic routing — round 14.
// B=64, N=4096, I=8, C=32, D=16, 3 routing iterations.
//
// Round-13 post-mortem: pass0 fix landed (~30us). pass12 x2 (~40us each) now
// dominates; VALU models at ~6us, memory ~10us -> the cost is the per-n-step
// serial chain through the block barrier (MFMA->cvt->fdot->shfl->exp->LDS->
// barrier->LDS->fmac, x16, 8 waves lockstepped, ~1 block/CU resident).
// Round 14 (pass12 only; pass0/reduce verbatim):
//  1) TWO n-steps per barrier: 16 -> 8 barriers. pd gains a sub-step axis;
//     double-buffer still race-free (write pre-bar, read post-bar, slot
//     reuse 2 epochs later).
//  2) fp16 accumulators (v_pk_fma_f16; round-7-verified pattern): acc
//     32 f32 fmac -> 16 pk-fma per n, and d-regs freed right after cvt ->
//     peak VGPR ~120 under the 128 cap despite 2 steps in flight.
//  3) epilogue stores acc h2 bits directly (no f32 pack).
//
// ws (NPB=16): Wh fp16 [n][cj][i] 32 MiB | partial u32(h2) 16 MiB |
//              xh fp16 [n][b][i] 4 MiB | OcumG fp16 [b][cj] 64 KiB (52.07)

typedef __fp16 h2 __attribute__((ext_vector_type(2)));
typedef __fp16 half4 __attribute__((ext_vector_type(4)));
typedef float f32x16 __attribute__((ext_vector_type(16)));

union U2 { h2 h; unsigned u; };

__device__ __forceinline__ float fdot2(h2 a, h2 b, float c) {
    return __builtin_amdgcn_fdot2(a, b, c, false);
}
__device__ __forceinline__ h2 uash2(unsigned u) { U2 t; t.u = u; return t.h; }

// ---- pass 0: uniform coupling; cj-split; LDS-staged x; emits Wh and xh ----

template <int NPB>
__global__ __launch_bounds__(512, 4) void pass0_kernel(
    const float* __restrict__ W,      // [C][N][D][I] f32
    const float* __restrict__ x,      // [B][N][I] f32
    ushort* __restrict__ Wh,          // [N][CJ][I] fp16
    ushort* __restrict__ xh,          // [N][B][I] fp16
    unsigned* __restrict__ partial)   // [(bt*NB+nblk)][bl 32][cjp 256] u32(h2)
{
    constexpr int NB = 4096 / NPB;
    const int bid = blockIdx.x;
    const int half = bid / NB, nblk = bid % NB;      // XCD = bid%8 = nblk%8
    const int n0 = nblk * NPB;
    const int t = threadIdx.x, l = t & 63, w = t >> 6;
    const int bl = l & 31, hi = l >> 5;
    const int cj = half * 256 + w * 32 + bl;         // this lane's A-row

    __shared__ __align__(16) ushort xs[NPB * 512];   // [n][b][i] fp16, swizzled
    __shared__ unsigned sep[8192];                   // 32KB epilogue staging

    // ---- stage x tile: coalesced f32 read -> fp16 -> swizzled LDS --------
    #pragma unroll
    for (int rep = 0; rep < NPB / 4; ++rep) {
        const int idx = t + rep * 512;               // float4 id, 0..NPB*128-1
        const int b = idx / (2 * NPB), f4 = idx % (2 * NPB);
        const int nl = f4 >> 1, isl = f4 & 1;
        float4 v = *reinterpret_cast<const float4*>(
            x + (size_t)b * 32768 + (size_t)n0 * 8 + f4 * 4);
        half4 h;
        h[0] = (__fp16)v.x; h[1] = (__fp16)v.y; h[2] = (__fp16)v.z; h[3] = (__fp16)v.w;
        const int slot = (nl * 128 + b * 2 + isl) ^ ((nl & 7) << 1) ^ ((b >> 3) & 3);
        *reinterpret_cast<half4*>(xs + slot * 4) = h;
    }
    __syncthreads();

    // ---- emit xh coalesced from LDS (half==0 blocks only) ----------------
    if (half == 0) {
        #pragma unroll
        for (int rep = 0; rep < NPB / 4; ++rep) {
            const int u = t + rep * 512;             // half4 id
            const int nl = u >> 7, b = (u >> 1) & 63, isl = u & 1;
            const int slot = (nl * 128 + b * 2 + isl) ^ ((nl & 7) << 1) ^ ((b >> 3) & 3);
            half4 h = *reinterpret_cast<const half4*>(xs + slot * 4);
            *reinterpret_cast<half4*>(xh + (size_t)n0 * 512 + u * 4) = h;
        }
    }

    const float* wb = W + (size_t)(cj >> 4) * 524288 + (size_t)n0 * 128 + (cj & 15) * 8 + hi * 4;
    ushort* whp = Wh + ((size_t)n0 * 512 + cj) * 8 + hi * 4;

    f32x16 acc0 = {}, acc1 = {};                     // b 0-31 / b 32-63
    float4 wv = *reinterpret_cast<const float4*>(wb);
    #pragma unroll 1
    for (int s = 0; s < NPB; ++s) {
        float4 wvn;
        if (s < NPB - 1)
            wvn = *reinterpret_cast<const float4*>(wb + (s + 1) * 128);
        const int sw = ((s & 7) << 1) ^ ((bl >> 3) & 3);
        const int slot0 = (s * 128 + bl * 2 + hi) ^ sw;
        const int slot1 = (s * 128 + bl * 2 + 64 + hi) ^ sw;
        half4 b0 = *reinterpret_cast<const half4*>(xs + slot0 * 4);
        half4 b1 = *reinterpret_cast<const half4*>(xs + slot1 * 4);
        half4 a;
        a[0] = (__fp16)wv.x; a[1] = (__fp16)wv.y; a[2] = (__fp16)wv.z; a[3] = (__fp16)wv.w;
        *reinterpret_cast<half4*>(whp + (size_t)s * 4096) = a;
        acc0 = __builtin_amdgcn_mfma_f32_32x32x8f16(a, b0, acc0, 0, 0, 0);
        acc1 = __builtin_amdgcn_mfma_f32_32x32x8f16(a, b1, acc1, 0, 0, 0);
        wv = wvn;
    }
    #pragma unroll
    for (int r = 0; r < 16; ++r) { acc0[r] *= 0.03125f; acc1[r] *= 0.03125f; }

    // epilogue: sep[b 64][cjp_local 128], XOR-swizzled by b
    #pragma unroll
    for (int hb = 0; hb < 2; ++hb) {
        #pragma unroll
        for (int q = 0; q < 8; ++q) {
            const float e0 = hb ? acc1[2 * q] : acc0[2 * q];
            const float e1 = hb ? acc1[2 * q + 1] : acc0[2 * q + 1];
            U2 u; u.h = __builtin_amdgcn_cvt_pkrtz(e0, e1);
            const int cjp = w * 16 + 4 * (q >> 1) + (q & 1) + 2 * hi;  // local
            const int bb = bl + 32 * hb;
            sep[bb * 128 + (cjp ^ bb)] = u.u;
        }
    }
    __syncthreads();
    #pragma unroll
    for (int u2 = 0; u2 < 16; ++u2) {
        const int idx = t + u2 * 512;                // 0..8191
        const int ub = idx >> 7, ucjp = idx & 127;
        partial[(size_t)((ub >> 5) * NB + nblk) * 8192 + (ub & 31) * 256 + half * 128 + ucjp]
            = sep[ub * 128 + (ucjp ^ ub)];
    }
}

// ---- pass 1/2: softmax coupling; 2 n-steps per barrier; fp16 acc ----------

template <int NPB>
__global__ __launch_bounds__(512, 4) void pass12_kernel(
    const ushort* __restrict__ Wh,    // [N][CJ][I] fp16
    const ushort* __restrict__ xh,    // [N][B][I] fp16
    const ushort* __restrict__ OcumG, // [B][CJ] fp16
    unsigned* __restrict__ partial)   // [bid][bl 32][cjp 256] u32(h2)
{
    constexpr int NB = 4096 / NPB;
    const int bid = blockIdx.x;
    const int bt = bid / NB, nblk = bid % NB;
    const int n0 = nblk * NPB;
    const int t = threadIdx.x, l = t & 63, w = t >> 6;
    const int bl = l & 31, hi = l >> 5;
    const int b = bt * 32 + bl;

    __shared__ __align__(16) float pd[2][2][32][12]; // [buf][sub][b][wave]
    __shared__ unsigned sep[8192];                   // 32KB epilogue staging

    const int cj0 = w * 64 + bl, cj1 = cj0 + 32;
    const ushort* xb = xh + ((size_t)n0 * 64 + b) * 8 + hi * 4;
    const ushort* whp0 = Wh + ((size_t)n0 * 512 + cj0) * 8 + hi * 4;
    const ushort* whp1 = Wh + ((size_t)n0 * 512 + cj1) * 8 + hi * 4;

    h2 oc[2][8];
    {
        const unsigned* og = reinterpret_cast<const unsigned*>(OcumG);
        #pragma unroll
        for (int mt = 0; mt < 2; ++mt) {
            const int cA = 4 * w + 2 * mt;
            const unsigned idx = (unsigned)b * 256 + cA * 8 + hi * 2;
            oc[mt][0] = uash2(og[idx]);      oc[mt][1] = uash2(og[idx + 1]);
            oc[mt][2] = uash2(og[idx + 4]);  oc[mt][3] = uash2(og[idx + 5]);
            oc[mt][4] = uash2(og[idx + 8]);  oc[mt][5] = uash2(og[idx + 9]);
            oc[mt][6] = uash2(og[idx + 12]); oc[mt][7] = uash2(og[idx + 13]);
        }
    }

    f32x16 zero = {};
    h2 acc0h[8], acc1h[8];                           // fp16 accumulators
    #pragma unroll
    for (int q = 0; q < 8; ++q) {
        acc0h[q] = (h2)(__fp16)0.f;
        acc1h[q] = (h2)(__fp16)0.f;
    }

    half4 a0A = *reinterpret_cast<const half4*>(whp0);
    half4 a1A = *reinterpret_cast<const half4*>(whp1);
    half4 bfA = *reinterpret_cast<const half4*>(xb);
    half4 a0B = *reinterpret_cast<const half4*>(whp0 + 4096);
    half4 a1B = *reinterpret_cast<const half4*>(whp1 + 4096);
    half4 bfB = *reinterpret_cast<const half4*>(xb + 512);

    #pragma unroll 1
    for (int p = 0; p < NPB / 2; ++p) {
        half4 a0An, a1An, bfAn, a0Bn, a1Bn, bfBn;
        if (p < NPB / 2 - 1) {
            const int sA = 2 * p + 2, sB = 2 * p + 3;
            a0An = *reinterpret_cast<const half4*>(whp0 + (size_t)sA * 4096);
            a1An = *reinterpret_cast<const half4*>(whp1 + (size_t)sA * 4096);
            bfAn = *reinterpret_cast<const half4*>(xb + (size_t)sA * 512);
            a0Bn = *reinterpret_cast<const half4*>(whp0 + (size_t)sB * 4096);
            a1Bn = *reinterpret_cast<const half4*>(whp1 + (size_t)sB * 4096);
            bfBn = *reinterpret_cast<const half4*>(xb + (size_t)sB * 512);
        }
        // ---- sub-step A -----------------------------------------------
        h2 hA0[8], hA1[8];
        {
            f32x16 d0 = __builtin_amdgcn_mfma_f32_32x32x8f16(a0A, bfA, zero, 0, 0, 0);
            f32x16 d1 = __builtin_amdgcn_mfma_f32_32x32x8f16(a1A, bfA, zero, 0, 0, 0);
            #pragma unroll
            for (int q = 0; q < 8; ++q) {
                hA0[q] = __builtin_amdgcn_cvt_pkrtz(d0[2 * q], d0[2 * q + 1]);
                hA1[q] = __builtin_amdgcn_cvt_pkrtz(d1[2 * q], d1[2 * q + 1]);
            }
        }
        float pA0_A = fdot2(hA0[3], oc[0][3], fdot2(hA0[2], oc[0][2], fdot2(hA0[1], oc[0][1], fdot2(hA0[0], oc[0][0], 0.f))));
        float pB0_A = fdot2(hA0[7], oc[0][7], fdot2(hA0[6], oc[0][6], fdot2(hA0[5], oc[0][5], fdot2(hA0[4], oc[0][4], 0.f))));
        float pA1_A = fdot2(hA1[3], oc[1][3], fdot2(hA1[2], oc[1][2], fdot2(hA1[1], oc[1][1], fdot2(hA1[0], oc[1][0], 0.f))));
        float pB1_A = fdot2(hA1[7], oc[1][7], fdot2(hA1[6], oc[1][6], fdot2(hA1[5], oc[1][5], fdot2(hA1[4], oc[1][4], 0.f))));
        // ---- sub-step B -----------------------------------------------
        h2 hB0[8], hB1[8];
        {
            f32x16 d0 = __builtin_amdgcn_mfma_f32_32x32x8f16(a0B, bfB, zero, 0, 0, 0);
            f32x16 d1 = __builtin_amdgcn_mfma_f32_32x32x8f16(a1B, bfB, zero, 0, 0, 0);
            #pragma unroll
            for (int q = 0; q < 8; ++q) {
                hB0[q] = __builtin_amdgcn_cvt_pkrtz(d0[2 * q], d0[2 * q + 1]);
                hB1[q] = __builtin_amdgcn_cvt_pkrtz(d1[2 * q], d1[2 * q + 1]);
            }
        }
        float pA0_B = fdot2(hB0[3], oc[0][3], fdot2(hB0[2], oc[0][2], fdot2(hB0[1], oc[0][1], fdot2(hB0[0], oc[0][0], 0.f))));
        float pB0_B = fdot2(hB0[7], oc[0][7], fdot2(hB0[6], oc[0][6], fdot2(hB0[5], oc[0][5], fdot2(hB0[4], oc[0][4], 0.f))));
        float pA1_B = fdot2(hB1[3], oc[1][3], fdot2(hB1[2], oc[1][2], fdot2(hB1[1], oc[1][1], fdot2(hB1[0], oc[1][0], 0.f))));
        float pB1_B = fdot2(hB1[7], oc[1][7], fdot2(hB1[6], oc[1][6], fdot2(hB1[5], oc[1][5], fdot2(hB1[4], oc[1][4], 0.f))));

        pA0_A += __shfl_xor(pA0_A, 32, 64);
        pB0_A += __shfl_xor(pB0_A, 32, 64);
        pA1_A += __shfl_xor(pA1_A, 32, 64);
        pB1_A += __shfl_xor(pB1_A, 32, 64);
        pA0_B += __shfl_xor(pA0_B, 32, 64);
        pB0_B += __shfl_xor(pB0_B, 32, 64);
        pA1_B += __shfl_xor(pA1_B, 32, 64);
        pB1_B += __shfl_xor(pB1_B, 32, 64);

        float eA0_A = __expf(pA0_A), eB0_A = __expf(pB0_A);
        float eA1_A = __expf(pA1_A), eB1_A = __expf(pB1_A);
        float eA0_B = __expf(pA0_B), eB0_B = __expf(pB0_B);
        float eA1_B = __expf(pA1_B), eB1_B = __expf(pB1_B);

        const int buf = p & 1;
        if (l < 32) {
            pd[buf][0][bl][w] = eA0_A + eB0_A + eA1_A + eB1_A;
            pd[buf][1][bl][w] = eA0_B + eB0_B + eA1_B + eB1_B;
        }
        __syncthreads();
        const float4 qa0 = *reinterpret_cast<const float4*>(&pd[buf][0][bl][0]);
        const float4 qa1 = *reinterpret_cast<const float4*>(&pd[buf][0][bl][4]);
        const float4 qb0 = *reinterpret_cast<const float4*>(&pd[buf][1][bl][0]);
        const float4 qb1 = *reinterpret_cast<const float4*>(&pd[buf][1][bl][4]);
        const float rdA = __builtin_amdgcn_rcpf(qa0.x + qa0.y + qa0.z + qa0.w +
                                                qa1.x + qa1.y + qa1.z + qa1.w);
        const float rdB = __builtin_amdgcn_rcpf(qb0.x + qb0.y + qb0.z + qb0.w +
                                                qb1.x + qb1.y + qb1.z + qb1.w);

        h2 c0A, c1A, c0B, c1B, c2A, c3A, c2B, c3B;
        c0A.x = (__fp16)(eA0_A * rdA); c0A.y = c0A.x;  // acc0 rows<8  (c=4w)
        c1A.x = (__fp16)(eB0_A * rdA); c1A.y = c1A.x;  // acc0 rows>=8 (c=4w+1)
        c2A.x = (__fp16)(eA1_A * rdA); c2A.y = c2A.x;  // acc1 rows<8  (c=4w+2)
        c3A.x = (__fp16)(eB1_A * rdA); c3A.y = c3A.x;  // acc1 rows>=8 (c=4w+3)
        c0B.x = (__fp16)(eA0_B * rdB); c0B.y = c0B.x;
        c1B.x = (__fp16)(eB0_B * rdB); c1B.y = c1B.x;
        c2B.x = (__fp16)(eA1_B * rdB); c2B.y = c2B.x;
        c3B.x = (__fp16)(eB1_B * rdB); c3B.y = c3B.x;

        #pragma unroll
        for (int q = 0; q < 4; ++q) {
            acc0h[q] = hA0[q] * c0A + acc0h[q];
            acc0h[q + 4] = hA0[q + 4] * c1A + acc0h[q + 4];
            acc1h[q] = hA1[q] * c2A + acc1h[q];
            acc1h[q + 4] = hA1[q + 4] * c3A + acc1h[q + 4];
        }
        #pragma unroll
        for (int q = 0; q < 4; ++q) {
            acc0h[q] = hB0[q] * c0B + acc0h[q];
            acc0h[q + 4] = hB0[q + 4] * c1B + acc0h[q + 4];
            acc1h[q] = hB1[q] * c2B + acc1h[q];
            acc1h[q + 4] = hB1[q + 4] * c3B + acc1h[q + 4];
        }
        a0A = a0An; a1A = a1An; bfA = bfAn;
        a0B = a0Bn; a1B = a1Bn; bfB = bfBn;
    }

    // ---- epilogue: stage h2 partial tile in LDS (XOR-swizzled), copy out --
    __syncthreads();
    #pragma unroll
    for (int mt = 0; mt < 2; ++mt) {
        #pragma unroll
        for (int q = 0; q < 8; ++q) {
            U2 u; u.h = mt ? acc1h[q] : acc0h[q];
            const int cjp = w * 32 + mt * 16 + 4 * (q >> 1) + (q & 1) + 2 * hi;
            sep[bl * 256 + (cjp ^ bl)] = u.u;   // swizzle: conflict-free banks
        }
    }
    __syncthreads();
    const unsigned gbase = (unsigned)bid * 8192;
    #pragma unroll
    for (int u2 = 0; u2 < 16; ++u2) {
        const int idx = t + u2 * 512;
        const int ubl = idx >> 8, ucjp = idx & 255;
        partial[gbase + idx] = sep[ubl * 256 + (ucjp ^ ubl)];
    }
}

// ---- final reduce + squash + Ocum update (4 threads per output) -----------

template <int NB>
__global__ __launch_bounds__(256) void reduce_squash(const unsigned* __restrict__ partial32,
                                                     ushort* __restrict__ OcumG,
                                                     float* __restrict__ out,
                                                     int passIdx) {
    const int gtid = blockIdx.x * 256 + threadIdx.x;  // 0..65535
    const int oid = gtid >> 2, sub = gtid & 3;
    const int b = oid >> 8, cjp = oid & 255;
    const int bt = b >> 5, bl = b & 31;
    const unsigned base = (unsigned)bt * (unsigned)NB * 8192u + (unsigned)bl * 256u + (unsigned)cjp;
    float sx = 0.f, sy = 0.f;
    #pragma unroll 8
    for (int i = 0; i < NB / 4; ++i) {
        U2 v; v.u = partial32[base + (unsigned)(sub + 4 * i) * 8192u];
        sx += (float)v.h.x;
        sy += (float)v.h.y;
    }
    sx += __shfl_xor(sx, 1, 64); sy += __shfl_xor(sy, 1, 64);
    sx += __shfl_xor(sx, 2, 64); sy += __shfl_xor(sy, 2, 64);
    float s2 = sx * sx + sy * sy;                    // sum over capsule's 8 cjp
    s2 += __shfl_xor(s2, 4, 64);
    s2 += __shfl_xor(s2, 8, 64);
    s2 += __shfl_xor(s2, 16, 64);
    float scale = (s2 / (1.f + s2)) / sqrtf(s2 + 1e-7f);
    float o0 = scale * sx, o1 = scale * sy;

    if (sub == 0) {
        unsigned* ocp = reinterpret_cast<unsigned*>(OcumG) + b * 256 + cjp;
        float a0 = o0, a1 = o1;
        if (passIdx) {
            U2 old; old.u = *ocp;
            a0 += (float)old.h.x;
            a1 += (float)old.h.y;
        }
        U2 nw; nw.h = __builtin_amdgcn_cvt_pkrtz(a0, a1);
        *ocp = nw.u;
        if (passIdx == 2) {
            out[b * 512 + cjp * 2] = o0;
            out[b * 512 + cjp * 2 + 1] = o1;
        }
    }
}

// ---- host ------------------------------------------------------------------

extern "C" void kernel_launch(void* const* d_in, const int* in_sizes, int n_in,
                              void* d_out, int out_size, void* d_ws, size_t ws_size,
                              hipStream_t stream) {
    const float* x = (const float*)d_in[0];
    const float* W = (const float*)d_in[1];
    float* out = (float*)d_out;

    char* ws = (char*)d_ws;
    ushort* Wh = (ushort*)ws;                                        // 32 MiB
    const size_t MiB = 1024 * 1024;

    if (ws_size >= 52 * MiB + 65536) {
        // NPB=16: partial 16 MiB | xh 4 MiB | Ocum 64 KiB
        unsigned* partialU = (unsigned*)(ws + 32 * MiB);
        ushort* xh = (ushort*)(ws + 48 * MiB);
        ushort* OcumG = (ushort*)(ws + 52 * MiB);
        pass0_kernel<16><<<512, 512, 0, stream>>>(W, x, Wh, xh, partialU);
        reduce_squash<256><<<256, 256, 0, stream>>>(partialU, OcumG, out, 0);
        pass12_kernel<16><<<512, 512, 0, stream>>>(Wh, xh, OcumG, partialU);
        reduce_squash<256><<<256, 256, 0, stream>>>(partialU, OcumG, out, 1);
        pass12_kernel<16><<<512, 512, 0, stream>>>(Wh, xh, OcumG, partialU);
        reduce_squash<256><<<256, 256, 0, stream>>>(partialU, OcumG, out, 2);
    } else {
        // fallback NPB=32: partial 8 MiB | xh 4 MiB | Ocum 64 KiB (44.07 MiB)
        unsigned* partialU = (unsigned*)(ws + 32 * MiB);
        ushort* xh = (ushort*)(ws + 40 * MiB);
        ushort* OcumG = (ushort*)(ws + 44 * MiB);
        pass0_kernel<32><<<256, 512, 0, stream>>>(W, x, Wh, xh, partialU);
        reduce_squash<128><<<256, 256, 0, stream>>>(partialU, OcumG, out, 0);
        pass12_kernel<32><<<256, 512, 0, stream>>>(Wh, xh, OcumG, partialU);
        reduce_squash<128><<<256, 256, 0, stream>>>(partialU, OcumG, out, 1);
        pass12_kernel<32><<<256, 512, 0, stream>>>(Wh, xh, OcumG, partialU);
        reduce_squash<128><<<256, 256, 0, stream>>>(partialU, OcumG, out, 2);
    }
}